// Round 1
// baseline (3445.693 us; speedup 1.0000x reference)
//
#include <hip/hip_runtime.h>
#include <cstdint>

typedef unsigned short u16;
typedef unsigned int   u32;
typedef __attribute__((ext_vector_type(8))) __bf16 bf16x8;
typedef __attribute__((ext_vector_type(4))) float  f32x4;
typedef __attribute__((ext_vector_type(4))) float  f4v;
typedef __attribute__((ext_vector_type(4))) short  s4v;

#define DI __device__ __forceinline__

DI u16 f2bf(float f){
  u32 u = __builtin_bit_cast(u32, f);
  u32 r = (u + 0x7FFFu + ((u >> 16) & 1u)) >> 16;
  return (u16)r;
}
DI float bf2f(u16 b){ return __builtin_bit_cast(float, (u32)b << 16); }

DI void gload16(const u16* g, u16* l){
  __builtin_amdgcn_global_load_lds((const __attribute__((address_space(1))) u32*)g,
                                   (__attribute__((address_space(3))) u32*)l, 16, 0, 0);
}

// ---------------- epilogues ----------------
struct EpiBias {            // C[r][c] = v + bias[c]  (fp32)
  float* C; const float* bias; int ldc; int M;
  DI void operator()(int bat, int r, int c, float v) const {
    if (r < M) C[(long)r*ldc + c] = v + bias[c];
  }
};
struct EpiStoreB {          // batched fp32 store (qk)
  float* C; long sC; int ldc;
  DI void operator()(int bat, int r, int c, float v) const {
    C[(long)bat*sC + (long)r*ldc + c] = v;
  }
};
struct EpiResid {           // X[r][c] += v + bias[c]
  float* X; const float* bias; int ldc; int M;
  DI void operator()(int bat, int r, int c, float v) const {
    if (r < M){ long i = (long)r*ldc + c; X[i] = X[i] + v + bias[c]; }
  }
};
struct EpiGelu {            // out = bf16(gelu(v+bias))
  u16* C; const float* bias; int ldc; int M;
  DI void operator()(int bat, int r, int c, float v) const {
    if (r < M){
      float x = v + bias[c];
      float g = 0.5f * x * (1.0f + erff(x * 0.70710678118654752440f));
      C[(long)r*ldc + c] = f2bf(g);
    }
  }
};
struct EpiPV {              // obuf[b, r, h*64+c] = bf16(v), r<196
  u16* O;
  DI void operator()(int bat, int r, int c, float v) const {
    if (r < 196){
      int b = bat / 12, h = bat % 12;
      O[((long)(b*196 + r))*768 + h*64 + c] = f2bf(v);
    }
  }
};

// ---------------- GEMM: C = A[M,K](bf16) * W[N,K]^T(bf16) ----------------
// 16x16x32 bf16 MFMA, BK=64, XOR chunk swizzle, global_load_lds staging.
template<int BM, int BN, int WM, int WN, class Epi>
__global__ __launch_bounds__(256)
void gemm_bf16(const u16* __restrict__ Ab, long sA, int lda, int M,
               const u16* __restrict__ Wb, long sW, int ldw, int K, Epi epi)
{
  constexpr int NTHR = WM*WN*64;
  __shared__ alignas(16) u16 As[BM*64];
  __shared__ alignas(16) u16 Bs[BN*64];
  const int tid  = threadIdx.x;
  const int wave = tid >> 6, lane = tid & 63;
  const int wm = wave % WM, wn = wave / WM;
  const int bn0 = blockIdx.x * BN;
  const int bm0 = blockIdx.y * BM;
  const int bat = blockIdx.z;
  const u16* A = Ab + (long)bat * sA;
  const u16* W = Wb + (long)bat * sW;

  f32x4 acc[4][4];
  #pragma unroll
  for (int i=0;i<4;i++)
    #pragma unroll
    for (int j=0;j<4;j++) acc[i][j] = (f32x4)0.0f;

  const int lrow = lane & 15, kq = lane >> 4;

  for (int k0 = 0; k0 < K; k0 += 64){
    #pragma unroll
    for (int it = 0; it < BM*8/NTHR; ++it){
      int s = tid + it*NTHR;
      int m = s >> 3, cg = (s & 7) ^ (m & 7);
      if (bm0 + m < M)
        gload16(A + (long)(bm0 + m)*lda + k0 + cg*8, &As[s*8]);
    }
    #pragma unroll
    for (int it = 0; it < BN*8/NTHR; ++it){
      int s = tid + it*NTHR;
      int n = s >> 3, cg = (s & 7) ^ (n & 7);
      gload16(W + (long)(bn0 + n)*ldw + k0 + cg*8, &Bs[s*8]);
    }
    __syncthreads();
    #pragma unroll
    for (int kh = 0; kh < 2; ++kh){
      bf16x8 af[4], bfr[4];
      #pragma unroll
      for (int mi=0; mi<4; mi++){
        int row = wm*64 + mi*16 + lrow;
        int c   = kh*4 + kq;
        af[mi] = *(const bf16x8*)&As[(row*8 + (c ^ (row & 7)))*8];
      }
      #pragma unroll
      for (int ni=0; ni<4; ni++){
        int col = wn*64 + ni*16 + lrow;
        int c   = kh*4 + kq;
        bfr[ni] = *(const bf16x8*)&Bs[(col*8 + (c ^ (col & 7)))*8];
      }
      #pragma unroll
      for (int mi=0; mi<4; mi++)
        #pragma unroll
        for (int ni=0; ni<4; ni++)
          acc[mi][ni] = __builtin_amdgcn_mfma_f32_16x16x32_bf16(af[mi], bfr[ni], acc[mi][ni], 0, 0, 0);
    }
    __syncthreads();
  }
  #pragma unroll
  for (int mi=0; mi<4; mi++)
    #pragma unroll
    for (int ni=0; ni<4; ni++)
      #pragma unroll
      for (int r=0; r<4; r++){
        int row = bm0 + wm*64 + mi*16 + (lane>>4)*4 + r;
        int col = bn0 + wn*64 + ni*16 + (lane & 15);
        epi(bat, row, col, acc[mi][ni][r]);
      }
}

// ---------------- misc kernels ----------------
__global__ __launch_bounds__(256)
void addpos_k(const float* __restrict__ x, const float* __restrict__ pos, float* __restrict__ xo)
{
  const int row = blockIdx.x, tid = threadIdx.x;
  const float* xr = x   + (long)row*768;
  const float* pr = pos + (long)(row % 196)*768;
  float* xw = xo + (long)row*768;
  xw[tid]     = xr[tid]     + pr[tid];
  xw[tid+256] = xr[tid+256] + pr[tid+256];
  xw[tid+512] = xr[tid+512] + pr[tid+512];
}

__global__ __launch_bounds__(256)
void cvt_k(const float* __restrict__ src, u16* __restrict__ dst, int n4)
{
  int i = blockIdx.x*256 + threadIdx.x;
  if (i < n4){
    f4v v = *(const f4v*)(src + (long)i*4);
    s4v o;
    o.x = (short)f2bf(v.x); o.y = (short)f2bf(v.y);
    o.z = (short)f2bf(v.z); o.w = (short)f2bf(v.w);
    *(s4v*)(dst + (long)i*4) = o;
  }
}

template<bool WX>
__global__ __launch_bounds__(256)
void ln768_k(const float* __restrict__ X, const float* __restrict__ g, const float* __restrict__ b,
             u16* __restrict__ hb, float* __restrict__ xo)
{
  const int row = blockIdx.x, tid = threadIdx.x;
  const float* xr = X + (long)row*768;
  float v0 = xr[tid], v1 = xr[tid+256], v2 = xr[tid+512];
  float s  = v0+v1+v2;
  float ss = v0*v0 + v1*v1 + v2*v2;
  #pragma unroll
  for (int o=32;o>=1;o>>=1){ s += __shfl_xor(s,o); ss += __shfl_xor(ss,o); }
  __shared__ float r1[4], r2[4];
  if ((tid&63)==0){ r1[tid>>6]=s; r2[tid>>6]=ss; }
  __syncthreads();
  s  = r1[0]+r1[1]+r1[2]+r1[3];
  ss = r2[0]+r2[1]+r2[2]+r2[3];
  float mean = s*(1.0f/768.0f);
  float var  = ss*(1.0f/768.0f) - mean*mean;
  float rstd = rsqrtf(var + 1e-5f);
  u16* hr = hb + (long)row*768;
  float* xw = xo ? xo + (long)row*768 : nullptr;
  int c = tid;
  float y0 = (v0-mean)*rstd*g[c] + b[c]; hr[c] = f2bf(y0); if (WX) xw[c] = y0;
  c = tid+256;
  float y1 = (v1-mean)*rstd*g[c] + b[c]; hr[c] = f2bf(y1); if (WX) xw[c] = y1;
  c = tid+512;
  float y2 = (v2-mean)*rstd*g[c] + b[c]; hr[c] = f2bf(y2); if (WX) xw[c] = y2;
}

__global__ __launch_bounds__(256)
void qkvln_k(const float* __restrict__ P, const float* __restrict__ g, const float* __restrict__ b,
             u16* __restrict__ q, u16* __restrict__ k, u16* __restrict__ v,
             float* __restrict__ qq, float* __restrict__ kk)
{
  const int row = blockIdx.x, tid = threadIdx.x;
  const int bb = row / 196, n = row % 196;
  const float* xr = P + (long)row*2304;
  float vv[9]; float s = 0.f, ss = 0.f;
  #pragma unroll
  for (int i=0;i<9;i++){ vv[i] = xr[tid + 256*i]; s += vv[i]; ss += vv[i]*vv[i]; }
  #pragma unroll
  for (int o=32;o>=1;o>>=1){ s += __shfl_xor(s,o); ss += __shfl_xor(ss,o); }
  __shared__ float r1[4], r2[4];
  if ((tid&63)==0){ r1[tid>>6]=s; r2[tid>>6]=ss; }
  __syncthreads();
  s  = r1[0]+r1[1]+r1[2]+r1[3];
  ss = r2[0]+r2[1]+r2[2]+r2[3];
  float mean = s*(1.0f/2304.0f);
  float var  = ss*(1.0f/2304.0f) - mean*mean;
  float rstd = rsqrtf(var + 1e-5f);
  __shared__ float y[2304];
  #pragma unroll
  for (int i=0;i<9;i++){ int c = tid + 256*i; y[c] = (vv[i]-mean)*rstd*g[c] + b[c]; }
  #pragma unroll
  for (int i=0;i<9;i++){
    int c = tid + 256*i;
    int si = c / 768, rem = c - si*768;
    int hh = rem >> 6, d = rem & 63;
    u16 hv = f2bf(y[c]);
    long dst = (((long)(bb*12 + hh))*256 + n)*64 + d;
    if (si == 0) q[dst] = hv; else if (si == 1) k[dst] = hv; else v[dst] = hv;
  }
  __syncthreads();
  if (tid < 24){
    int si = tid / 12, hh = tid % 12;
    const float* yb = y + si*768 + hh*64;
    float a = 0.f;
    #pragma unroll
    for (int d=0; d<64; d++){ float t = bf2f(f2bf(yb[d])); a += t*t; }
    float* dst = (si == 0) ? qq : kk;
    dst[(bb*12 + hh)*256 + n] = a;
  }
}

__global__ __launch_bounds__(256)
void vtr_k(const u16* __restrict__ vtmp, u16* __restrict__ vT)
{
  const int bh = blockIdx.x, tid = threadIdx.x;
  const u16* src = vtmp + (long)bh*(256*64);
  u16* dst = vT + (long)bh*(64*256);
  __shared__ u16 t[64][65];
  for (int n0 = 0; n0 < 256; n0 += 64){
    #pragma unroll
    for (int i=0;i<16;i++){
      int idx = tid + i*256;
      int nn = idx >> 6, d = idx & 63;
      int n = n0 + nn;
      t[d][nn] = (n < 196) ? src[(long)n*64 + d] : (u16)0;
    }
    __syncthreads();
    #pragma unroll
    for (int i=0;i<16;i++){
      int idx = tid + i*256;
      int d = idx >> 6, nn = idx & 63;
      dst[(long)d*256 + n0 + nn] = t[d][nn];   // pads written as zero
    }
    __syncthreads();
  }
}

// fused: riem + BN + temp + conv-mix + softmax -> p (bf16, [B,H,256,256], pads zero)
__global__ __launch_bounds__(256)
void mix_k(const float* __restrict__ qk, const float* __restrict__ qq, const float* __restrict__ kk,
           const float* __restrict__ cw, const float* __restrict__ cb,
           const float* __restrict__ bng, const float* __restrict__ bnb,
           const float* __restrict__ temp, const float* __restrict__ scale_p,
           const float* __restrict__ rscale_p, u16* __restrict__ p)
{
  const int i = blockIdx.x, b = blockIdx.y, tid = threadIdx.x;
  __shared__ float cA[12][12], cB[12][12], K0[12], qq2[12];
  __shared__ float kk2[12*196];
  __shared__ float vals[12][256];
  const float BNR = 0.99999500003749969f;
  const float scale = scale_p[0], rscale = rscale_p[0];
  if (tid < 144){
    int h = tid / 12, m = tid % 12;
    cA[h][m] = cw[h*24 + m]      * scale  * temp[m]    * BNR * bng[m];
    cB[h][m] = cw[h*24 + 12 + m] * rscale * temp[12+m] * BNR * bng[12+m];
  } else if (tid < 156){
    int h = tid - 144;
    float a = cb[h];
    for (int c2 = 0; c2 < 24; c2++) a += cw[h*24 + c2] * bnb[c2];
    K0[h] = a;
  } else if (tid < 168){
    int m = tid - 156;
    float t = qq[(b*12 + m)*256 + i];
    qq2[m] = t*t;
  }
  for (int idx = tid; idx < 12*196; idx += 256){
    int m = idx / 196, j = idx - m*196;
    float t = kk[(b*12 + m)*256 + j];
    kk2[idx] = t*t;
  }
  __syncthreads();
  const int j = tid;
  if (j < 196){
    float vh[12];
    #pragma unroll
    for (int h=0; h<12; h++) vh[h] = K0[h];
    const float* qkb = qk + ((long)(b*12)*256 + i)*256 + j;
    #pragma unroll
    for (int m=0; m<12; m++){
      float qv = qkb[(long)m*65536];
      float dd = qq2[m] + kk2[m*196 + j] - 2.0f*qv*qv;
      float r  = sqrtf(fmaxf(dd, 0.0f) + 1e-12f);
      #pragma unroll
      for (int h=0; h<12; h++) vh[h] += cA[h][m]*qv + cB[h][m]*r;
    }
    #pragma unroll
    for (int h=0; h<12; h++) vals[h][j] = vh[h];
  }
  __syncthreads();
  const int wv = tid >> 6, lane = tid & 63;
  for (int t3 = 0; t3 < 3; t3++){
    int h = wv*3 + t3;
    float e0 = vals[h][lane], e1 = vals[h][lane+64], e2 = vals[h][lane+128];
    float e3 = (lane < 4) ? vals[h][192 + lane] : -3.4e38f;
    float mx = fmaxf(fmaxf(e0,e1), fmaxf(e2,e3));
    #pragma unroll
    for (int o=32;o>=1;o>>=1) mx = fmaxf(mx, __shfl_xor(mx,o));
    e0 = expf(e0 - mx); e1 = expf(e1 - mx); e2 = expf(e2 - mx);
    e3 = (lane < 4) ? expf(e3 - mx) : 0.0f;
    float sm = e0 + e1 + e2 + e3;
    #pragma unroll
    for (int o=32;o>=1;o>>=1) sm += __shfl_xor(sm,o);
    float inv = 1.0f / sm;
    u16* pr = p + (((long)(b*12 + h))*256 + i)*256;
    pr[lane]       = f2bf(e0*inv);
    pr[lane + 64]  = f2bf(e1*inv);
    pr[lane + 128] = f2bf(e2*inv);
    pr[lane + 192] = (lane < 4) ? f2bf(e3*inv) : (u16)0;
  }
}

__global__ __launch_bounds__(256)
void lnpool_k(float* __restrict__ X, const float* __restrict__ g, const float* __restrict__ b,
              const float* __restrict__ pw, const float* __restrict__ pb, float* __restrict__ sout)
{
  const int row = blockIdx.x, tid = threadIdx.x;
  float* xr = X + (long)row*768;
  float v0 = xr[tid], v1 = xr[tid+256], v2 = xr[tid+512];
  float s = v0+v1+v2, ss = v0*v0+v1*v1+v2*v2;
  #pragma unroll
  for (int o=32;o>=1;o>>=1){ s += __shfl_xor(s,o); ss += __shfl_xor(ss,o); }
  __shared__ float r1[4], r2[4];
  if ((tid&63)==0){ r1[tid>>6]=s; r2[tid>>6]=ss; }
  __syncthreads();
  s  = r1[0]+r1[1]+r1[2]+r1[3];
  ss = r2[0]+r2[1]+r2[2]+r2[3];
  float mean = s*(1.0f/768.0f);
  float rstd = rsqrtf(ss*(1.0f/768.0f) - mean*mean + 1e-5f);
  float y0 = (v0-mean)*rstd*g[tid]     + b[tid];
  float y1 = (v1-mean)*rstd*g[tid+256] + b[tid+256];
  float y2 = (v2-mean)*rstd*g[tid+512] + b[tid+512];
  xr[tid] = y0; xr[tid+256] = y1; xr[tid+512] = y2;
  float dot = y0*pw[tid] + y1*pw[tid+256] + y2*pw[tid+512];
  __syncthreads();
  #pragma unroll
  for (int o=32;o>=1;o>>=1) dot += __shfl_xor(dot,o);
  if ((tid&63)==0) r1[tid>>6] = dot;
  __syncthreads();
  if (tid == 0) sout[row] = r1[0]+r1[1]+r1[2]+r1[3] + pb[0];
}

__global__ __launch_bounds__(256)
void pool_k(const float* __restrict__ X, const float* __restrict__ s, float* __restrict__ pooled)
{
  const int b = blockIdx.x, tid = threadIdx.x;
  __shared__ float red[4];
  __shared__ float w[256];
  float v = (tid < 196) ? s[b*196 + tid] : -3.4e38f;
  float mx = v;
  #pragma unroll
  for (int o=32;o>=1;o>>=1) mx = fmaxf(mx, __shfl_xor(mx,o));
  if ((tid&63)==0) red[tid>>6] = mx;
  __syncthreads();
  mx = fmaxf(fmaxf(red[0],red[1]), fmaxf(red[2],red[3]));
  __syncthreads();
  float e = (tid < 196) ? expf(v - mx) : 0.0f;
  float sm = e;
  #pragma unroll
  for (int o=32;o>=1;o>>=1) sm += __shfl_xor(sm,o);
  if ((tid&63)==0) red[tid>>6] = sm;
  __syncthreads();
  sm = red[0]+red[1]+red[2]+red[3];
  w[tid] = e / sm;
  __syncthreads();
  for (int c = tid; c < 768; c += 256){
    float acc = 0.0f;
    for (int n = 0; n < 196; n++) acc += w[n] * X[((long)b*196 + n)*768 + c];
    pooled[b*768 + c] = acc;
  }
}

__global__ __launch_bounds__(256)
void fc_k(const float* __restrict__ pooled, const float* __restrict__ fw,
          const float* __restrict__ fb, float* __restrict__ out)
{
  const int tid = threadIdx.x;
  __shared__ float pl[16][769];
  for (int idx = tid; idx < 16*768; idx += 256) pl[idx/768][idx%768] = pooled[idx];
  __syncthreads();
  int o = blockIdx.x*16 + (tid >> 4);
  int b = tid & 15;
  if (o < 1000){
    float acc = 0.0f;
    const float* fr = fw + (long)o*768;
    for (int c = 0; c < 768; c++) acc += pl[b][c] * fr[c];
    out[b*1000 + o] = acc + fb[o];
  }
}

// ---------------- launch ----------------
extern "C" void kernel_launch(void* const* d_in, const int* in_sizes, int n_in,
                              void* d_out, int out_size, void* d_ws, size_t ws_size,
                              hipStream_t stream)
{
  const float* x_in   = (const float*)d_in[0];
  const float* pos    = (const float*)d_in[1];
  const float* ln0_g  = (const float*)d_in[2];
  const float* ln0_b  = (const float*)d_in[3];
  const float* qkv_w  = (const float*)d_in[4];
  const float* qkv_b  = (const float*)d_in[5];
  const float* qln_g  = (const float*)d_in[6];
  const float* qln_b  = (const float*)d_in[7];
  const float* scale  = (const float*)d_in[8];
  const float* rscale = (const float*)d_in[9];
  const float* temp   = (const float*)d_in[10];
  const float* bn_g   = (const float*)d_in[11];
  const float* bn_b   = (const float*)d_in[12];
  const float* conv_w = (const float*)d_in[13];
  const float* conv_b = (const float*)d_in[14];
  const float* proj_w = (const float*)d_in[15];
  const float* proj_b = (const float*)d_in[16];
  const float* ln1_g  = (const float*)d_in[17];
  const float* ln1_b  = (const float*)d_in[18];
  const float* ff1_w  = (const float*)d_in[19];
  const float* ff1_b  = (const float*)d_in[20];
  const float* ff2_w  = (const float*)d_in[21];
  const float* ff2_b  = (const float*)d_in[22];
  const float* nrm_g  = (const float*)d_in[23];
  const float* nrm_b  = (const float*)d_in[24];
  const float* pool_w = (const float*)d_in[25];
  const float* pool_b = (const float*)d_in[26];
  const float* fc_w   = (const float*)d_in[27];
  const float* fc_b   = (const float*)d_in[28];

  char* base = (char*)d_ws; size_t off = 0;
  auto carve = [&](size_t bytes)->void*{
    void* pp = base + off; off += (bytes + 255) & ~(size_t)255; return pp;
  };
  float* x_ws  = (float*)carve(3136L*768*4);
  u16*   hbuf  = (u16*)  carve(3136L*768*2);
  float* qkvp  = (float*)carve(3136L*2304*4);
  u16*   qb    = (u16*)  carve(192L*256*64*2);
  u16*   kb    = (u16*)  carve(192L*256*64*2);
  u16*   vtmp  = (u16*)  carve(192L*256*64*2);
  u16*   vT    = (u16*)  carve(192L*64*256*2);
  float* qqb   = (float*)carve(192L*256*4);
  float* kkb   = (float*)carve(192L*256*4);
  float* qkf   = (float*)carve(192L*65536*4);
  u16*   pb    = (u16*)  carve(192L*65536*2);
  u16*   obuf  = (u16*)  carve(3136L*768*2);
  u16*   fbuf  = (u16*)  carve(3136L*3072*2);
  u16*   wqkv  = (u16*)  carve(2304L*768*2);
  u16*   wproj = (u16*)  carve(768L*768*2);
  u16*   wff1  = (u16*)  carve(3072L*768*2);
  u16*   wff2  = (u16*)  carve(768L*3072*2);
  float* sbuf  = (float*)carve(3136L*4);
  float* pooled= (float*)carve(16L*768*4);

  addpos_k<<<3136, 256, 0, stream>>>(x_in, pos, x_ws);

  for (int l = 0; l < 12; l++){
    cvt_k<<<(2304*768/4 + 255)/256, 256, 0, stream>>>(qkv_w + (long)l*2304*768, wqkv, 2304*768/4);
    cvt_k<<<( 768*768/4 + 255)/256, 256, 0, stream>>>(proj_w + (long)l*768*768, wproj, 768*768/4);
    cvt_k<<<(3072*768/4 + 255)/256, 256, 0, stream>>>(ff1_w + (long)l*3072*768, wff1, 3072*768/4);
    cvt_k<<<(3072*768/4 + 255)/256, 256, 0, stream>>>(ff2_w + (long)l*768*3072, wff2, 768*3072/4);

    ln768_k<false><<<3136, 256, 0, stream>>>(x_ws, ln0_g + l*768, ln0_b + l*768, hbuf, nullptr);

    gemm_bf16<128,128,2,2><<<dim3(18,25,1), 256, 0, stream>>>(
        hbuf, 0L, 768, 3136, wqkv, 0L, 768, 768,
        EpiBias{qkvp, qkv_b + (long)l*2304, 2304, 3136});

    qkvln_k<<<3136, 256, 0, stream>>>(qkvp, qln_g + (long)l*2304, qln_b + (long)l*2304,
                                      qb, kb, vtmp, qqb, kkb);
    vtr_k<<<192, 256, 0, stream>>>(vtmp, vT);

    gemm_bf16<128,128,2,2><<<dim3(2,2,192), 256, 0, stream>>>(
        qb, 16384L, 64, 256, kb, 16384L, 64, 64,
        EpiStoreB{qkf, 65536L, 256});

    mix_k<<<dim3(196,16), 256, 0, stream>>>(qkf, qqb, kkb,
        conv_w + (long)l*288, conv_b + (long)l*12, bn_g + (long)l*24, bn_b + (long)l*24,
        temp + (long)l*24, scale + l, rscale + l, pb);

    gemm_bf16<256,64,4,1><<<dim3(1,1,192), 256, 0, stream>>>(
        pb, 65536L, 256, 256, vT, 16384L, 256, 256,
        EpiPV{obuf});

    gemm_bf16<128,128,2,2><<<dim3(6,25,1), 256, 0, stream>>>(
        obuf, 0L, 768, 3136, wproj, 0L, 768, 768,
        EpiResid{x_ws, proj_b + (long)l*768, 768, 3136});

    ln768_k<true><<<3136, 256, 0, stream>>>(x_ws, ln1_g + l*768, ln1_b + l*768, hbuf, x_ws);

    gemm_bf16<128,128,2,2><<<dim3(24,25,1), 256, 0, stream>>>(
        hbuf, 0L, 768, 3136, wff1, 0L, 768, 768,
        EpiGelu{fbuf, ff1_b + (long)l*3072, 3072, 3136});

    gemm_bf16<128,128,2,2><<<dim3(6,25,1), 256, 0, stream>>>(
        fbuf, 0L, 3072, 3136, wff2, 0L, 3072, 3072,
        EpiResid{x_ws, ff2_b + (long)l*768, 768, 3136});
  }

  lnpool_k<<<3136, 256, 0, stream>>>(x_ws, nrm_g, nrm_b, pool_w, pool_b, sbuf);
  pool_k<<<16, 256, 0, stream>>>(x_ws, sbuf, pooled);
  fc_k<<<63, 256, 0, stream>>>(pooled, fc_w, fc_b, (float*)d_out);
}